// Round 1
// baseline (1564.463 us; speedup 1.0000x reference)
//
#include <hip/hip_runtime.h>
#include <math.h>

#define C_DIM 512
#define N_DIM 4096
#define BATCH 16
#define NHEADS 8
#define NGROUPS 8

// -------------------- K1: per-channel sums (double accum) --------------------
__global__ __launch_bounds__(256) void channel_stats_kernel(
    const float* __restrict__ x, double* __restrict__ chsum, double* __restrict__ chsq) {
  int bc = blockIdx.x;  // b*C + c
  const float4* p = (const float4*)(x + (size_t)bc * N_DIM);
  double s = 0.0, ss = 0.0;
  for (int i = threadIdx.x; i < N_DIM / 4; i += 256) {
    float4 v = p[i];
    s  += (double)v.x + (double)v.y + (double)v.z + (double)v.w;
    ss += (double)v.x * v.x + (double)v.y * v.y + (double)v.z * v.z + (double)v.w * v.w;
  }
  __shared__ double rs[256], rss[256];
  int t = threadIdx.x;
  rs[t] = s; rss[t] = ss;
  __syncthreads();
  for (int o = 128; o > 0; o >>= 1) {
    if (t < o) { rs[t] += rs[t + o]; rss[t] += rss[t + o]; }
    __syncthreads();
  }
  if (t == 0) { chsum[bc] = rs[0]; chsq[bc] = rss[0]; }
}

// ---------- K1b: group stats -> per-(b,c) affine coef a,d and rowsum s ----------
__global__ __launch_bounds__(64) void group_stats_kernel(
    const double* __restrict__ chsum, const double* __restrict__ chsq,
    const float* __restrict__ gamma, const float* __restrict__ beta,
    float* __restrict__ a_coef, float* __restrict__ d_coef, float* __restrict__ svec) {
  int b = blockIdx.x / NGROUPS, g = blockIdx.x % NGROUPS;
  int c = g * 64 + threadIdx.x;
  int idx = b * C_DIM + c;
  double cs = chsum[idx], cq = chsq[idx];
  double s = cs, ss = cq;
  for (int o = 32; o > 0; o >>= 1) { s += __shfl_xor(s, o, 64); ss += __shfl_xor(ss, o, 64); }
  const double M = 64.0 * 4096.0;
  double mean = s / M;
  double var = ss / M - mean * mean;
  double rstd = 1.0 / sqrt(var + 1e-5);
  double a = rstd * (double)gamma[c];
  double d = (double)beta[c] - mean * a;
  a_coef[idx] = (float)a;
  d_coef[idx] = (float)d;
  // s_b[c] = sum_n h[c,n] = a * chsum + 4096 * d
  svec[idx] = (float)(a * cs + 4096.0 * d);
}

// 8x8 microtile MAC from As/Bs [32][128]
#define MAC8x8(As, Bs)                                               \
  do {                                                               \
    float4 a0 = *(const float4*)&As[k][ty * 8];                      \
    float4 a1 = *(const float4*)&As[k][ty * 8 + 4];                  \
    float4 b0 = *(const float4*)&Bs[k][tx * 8];                      \
    float4 b1 = *(const float4*)&Bs[k][tx * 8 + 4];                  \
    float ar[8] = {a0.x, a0.y, a0.z, a0.w, a1.x, a1.y, a1.z, a1.w};  \
    float br[8] = {b0.x, b0.y, b0.z, b0.w, b1.x, b1.y, b1.z, b1.w};  \
    _Pragma("unroll") for (int i_ = 0; i_ < 8; ++i_) {               \
      _Pragma("unroll") for (int j_ = 0; j_ < 8; ++j_)               \
        acc[i_][j_] += ar[i_] * br[j_];                              \
    }                                                                \
  } while (0)

// -------------------- K2: Gram G_b = h_b h_b^T  (NT, K = 4096) --------------------
__global__ __launch_bounds__(256) void gram_kernel(
    const float* __restrict__ x, const float* __restrict__ na, const float* __restrict__ nd,
    float* __restrict__ G) {
  int b = blockIdx.y;
  int ti = blockIdx.x >> 2, tj = blockIdx.x & 3;
  int i0 = ti * 128, j0 = tj * 128;
  const float* xb = x + (size_t)b * C_DIM * N_DIM;
  __shared__ float As[32][128], Bs[32][128];
  __shared__ float caA[128], cdA[128], caB[128], cdB[128];
  int t = threadIdx.x, tx = t & 15, ty = t >> 4;
  if (t < 128) { caA[t] = na[b * C_DIM + i0 + t]; cdA[t] = nd[b * C_DIM + i0 + t]; }
  else { int r = t - 128; caB[r] = na[b * C_DIM + j0 + r]; cdB[r] = nd[b * C_DIM + j0 + r]; }
  __syncthreads();
  float acc[8][8] = {};
  for (int kt = 0; kt < N_DIM; kt += 32) {
#pragma unroll
    for (int r = 0; r < 4; ++r) {
      int idx = t + r * 256;
      int row = idx >> 3, c4 = (idx & 7) * 4;
      float4 v = *(const float4*)(xb + (size_t)(i0 + row) * N_DIM + kt + c4);
      float a = caA[row], d = cdA[row];
      As[c4 + 0][row] = a * v.x + d; As[c4 + 1][row] = a * v.y + d;
      As[c4 + 2][row] = a * v.z + d; As[c4 + 3][row] = a * v.w + d;
      float4 w = *(const float4*)(xb + (size_t)(j0 + row) * N_DIM + kt + c4);
      float ab = caB[row], db = cdB[row];
      Bs[c4 + 0][row] = ab * w.x + db; Bs[c4 + 1][row] = ab * w.y + db;
      Bs[c4 + 2][row] = ab * w.z + db; Bs[c4 + 3][row] = ab * w.w + db;
    }
    __syncthreads();
#pragma unroll 4
    for (int k = 0; k < 32; ++k) { MAC8x8(As, Bs); }
    __syncthreads();
  }
  float* Gb = G + (size_t)b * C_DIM * C_DIM;
#pragma unroll
  for (int i = 0; i < 8; ++i) {
    int r = i0 + ty * 8 + i;
    float4 w0 = make_float4(acc[i][0], acc[i][1], acc[i][2], acc[i][3]);
    float4 w1 = make_float4(acc[i][4], acc[i][5], acc[i][6], acc[i][7]);
    *(float4*)(Gb + (size_t)r * C_DIM + j0 + tx * 8) = w0;
    *(float4*)(Gb + (size_t)r * C_DIM + j0 + tx * 8 + 4) = w1;
  }
}

// ---------- generic NN GEMM: C[b] = A[b] @ B[b] (M=512, K=512, N=ncols) ----------
// optional: per-(b,k) affine norm of B rows; optional epilogue out = resid + acc + cvec[row]
__global__ __launch_bounds__(256) void nn_gemm_kernel(
    const float* __restrict__ A, long sA,
    const float* __restrict__ B, long sB,
    float* __restrict__ Cout, long sC, int ncols,
    const float* __restrict__ na, const float* __restrict__ nd,
    const float* __restrict__ resid, const float* __restrict__ cvec) {
  int b = blockIdx.y;
  int tilesj = ncols >> 7;
  int ti = blockIdx.x / tilesj, tj = blockIdx.x - ti * tilesj;
  int i0 = ti * 128, j0 = tj * 128;
  const float* Ab = A + (size_t)b * sA;
  const float* Bb = B + (size_t)b * sB;
  __shared__ float As[32][128], Bs[32][128];
  int t = threadIdx.x, tx = t & 15, ty = t >> 4;
  float acc[8][8] = {};
  for (int kt = 0; kt < C_DIM; kt += 32) {
#pragma unroll
    for (int r = 0; r < 4; ++r) {
      int idx = t + r * 256;
      { // A tile -> transposed
        int row = idx >> 3, c4 = (idx & 7) * 4;
        float4 v = *(const float4*)(Ab + (size_t)(i0 + row) * C_DIM + kt + c4);
        As[c4 + 0][row] = v.x; As[c4 + 1][row] = v.y; As[c4 + 2][row] = v.z; As[c4 + 3][row] = v.w;
      }
      { // B tile -> direct
        int kr = idx >> 5, c4 = (idx & 31) * 4;
        float4 v = *(const float4*)(Bb + (size_t)(kt + kr) * ncols + j0 + c4);
        if (na) {
          float a = na[b * C_DIM + kt + kr], d = nd[b * C_DIM + kt + kr];
          v.x = a * v.x + d; v.y = a * v.y + d; v.z = a * v.z + d; v.w = a * v.w + d;
        }
        *(float4*)&Bs[kr][c4] = v;
      }
    }
    __syncthreads();
#pragma unroll 4
    for (int k = 0; k < 32; ++k) { MAC8x8(As, Bs); }
    __syncthreads();
  }
#pragma unroll
  for (int i = 0; i < 8; ++i) {
    int r = i0 + ty * 8 + i;
    size_t off = (size_t)b * sC + (size_t)r * ncols + j0 + tx * 8;
    float4 w0 = make_float4(acc[i][0], acc[i][1], acc[i][2], acc[i][3]);
    float4 w1 = make_float4(acc[i][4], acc[i][5], acc[i][6], acc[i][7]);
    if (resid) {
      float cv = cvec[b * C_DIM + r];
      float4 x0 = *(const float4*)(resid + off);
      float4 x1 = *(const float4*)(resid + off + 4);
      w0.x += x0.x + cv; w0.y += x0.y + cv; w0.z += x0.z + cv; w0.w += x0.w + cv;
      w1.x += x1.x + cv; w1.y += x1.y + cv; w1.z += x1.z + cv; w1.w += x1.w + cv;
    }
    *(float4*)(Cout + off) = w0;
    *(float4*)(Cout + off + 4) = w1;
  }
}

// ---------- K3b: per-(b,h) attention: att = softmax((Wq G Wk^T + bias)/8); ----------
// P_bh = att @ Wv_h ; u_bh = att @ bv_h
__global__ __launch_bounds__(256) void attn_kernel(
    const float* __restrict__ QG, const float* __restrict__ w_qkv,
    const float* __restrict__ b_qkv, const float* __restrict__ svec,
    float* __restrict__ P, float* __restrict__ u) {
  int h = blockIdx.x, b = blockIdx.y;
  __shared__ float s_sh[512];
  __shared__ float qs[64], ks[64], bqv[64], bkv[64], bvv[64];
  __shared__ float pool[4096];   // As(2048) + Bs(2048), later Ws(4096)
  __shared__ float att[64][66];
  int t = threadIdx.x, tx = t & 15, ty = t >> 4;
  for (int i = t; i < 512; i += 256) s_sh[i] = svec[b * C_DIM + i];
  if (t < 64) {
    bqv[t] = b_qkv[h * 64 + t];
    bkv[t] = b_qkv[512 + h * 64 + t];
    bvv[t] = b_qkv[1024 + h * 64 + t];
  }
  __syncthreads();
  if (t < 64) {            // qs_d = (Wq_h s)_d
    const float* wr = w_qkv + (size_t)(h * 64 + t) * C_DIM;
    float a = 0.f;
    for (int c = 0; c < 512; ++c) a += wr[c] * s_sh[c];
    qs[t] = a;
  } else if (t < 128) {    // ks_e = (Wk_h s)_e
    int e = t - 64;
    const float* wr = w_qkv + (size_t)(512 + h * 64 + e) * C_DIM;
    float a = 0.f;
    for (int c = 0; c < 512; ++c) a += wr[c] * s_sh[c];
    ks[e] = a;
  }
  __syncthreads();
  // phase 1: mm[d,e] = sum_c QG[h64+d, c] * Wk[h64+e, c]   (NT, K=512)
  float acc[4][4] = {};
  float* As = pool;          // As[k][row] : [32][64]
  float* Bs = pool + 2048;
  for (int kt = 0; kt < 512; kt += 32) {
#pragma unroll
    for (int r = 0; r < 2; ++r) {
      int idx = t + r * 256;
      int row = idx >> 3, c4 = (idx & 7) * 4;
      float4 va = *(const float4*)(QG + ((size_t)b * 512 + h * 64 + row) * 512 + kt + c4);
      As[(c4 + 0) * 64 + row] = va.x; As[(c4 + 1) * 64 + row] = va.y;
      As[(c4 + 2) * 64 + row] = va.z; As[(c4 + 3) * 64 + row] = va.w;
      float4 vb = *(const float4*)(w_qkv + (size_t)(512 + h * 64 + row) * 512 + kt + c4);
      Bs[(c4 + 0) * 64 + row] = vb.x; Bs[(c4 + 1) * 64 + row] = vb.y;
      Bs[(c4 + 2) * 64 + row] = vb.z; Bs[(c4 + 3) * 64 + row] = vb.w;
    }
    __syncthreads();
#pragma unroll 4
    for (int k = 0; k < 32; ++k) {
      float4 a4 = *(const float4*)&As[k * 64 + ty * 4];
      float4 b4 = *(const float4*)&Bs[k * 64 + tx * 4];
      float ar[4] = {a4.x, a4.y, a4.z, a4.w};
      float br[4] = {b4.x, b4.y, b4.z, b4.w};
#pragma unroll
      for (int i = 0; i < 4; ++i)
#pragma unroll
        for (int j = 0; j < 4; ++j) acc[i][j] += ar[i] * br[j];
    }
    __syncthreads();
  }
  // phase 2: bias + scale
#pragma unroll
  for (int i = 0; i < 4; ++i) {
    int d = ty * 4 + i;
#pragma unroll
    for (int j = 0; j < 4; ++j) {
      int e = tx * 4 + j;
      float raw = acc[i][j] + bqv[d] * ks[e] + bkv[e] * qs[d] + 4096.0f * bqv[d] * bkv[e];
      att[d][e] = raw * 0.125f;
    }
  }
  __syncthreads();
  // phase 3: softmax over e (rows d)
  if (t < 64) {
    float m = -1e30f;
    for (int e = 0; e < 64; ++e) m = fmaxf(m, att[t][e]);
    float ssum = 0.f;
    for (int e = 0; e < 64; ++e) { float p = expf(att[t][e] - m); att[t][e] = p; ssum += p; }
    float inv = 1.0f / ssum;
    for (int e = 0; e < 64; ++e) att[t][e] *= inv;
  }
  __syncthreads();
  // phase 4: P_bh[d, c] = sum_e att[d,e] * Wv[h64+e, c]
  float* Ws = pool;  // [64 e][64 c]
  for (int cc = 0; cc < 512; cc += 64) {
#pragma unroll
    for (int r = 0; r < 4; ++r) {
      int idx = t + r * 256;
      int row = idx >> 4, c4 = (idx & 15) * 4;
      *(float4*)&Ws[row * 64 + c4] =
          *(const float4*)(w_qkv + (size_t)(1024 + h * 64 + row) * 512 + cc + c4);
    }
    __syncthreads();
    float pacc[4][4] = {};
#pragma unroll 4
    for (int e = 0; e < 64; ++e) {
      float a0 = att[ty * 4 + 0][e], a1 = att[ty * 4 + 1][e];
      float a2 = att[ty * 4 + 2][e], a3 = att[ty * 4 + 3][e];
      float4 b4 = *(const float4*)&Ws[e * 64 + tx * 4];
      float br[4] = {b4.x, b4.y, b4.z, b4.w};
#pragma unroll
      for (int j = 0; j < 4; ++j) {
        pacc[0][j] += a0 * br[j]; pacc[1][j] += a1 * br[j];
        pacc[2][j] += a2 * br[j]; pacc[3][j] += a3 * br[j];
      }
    }
#pragma unroll
    for (int i = 0; i < 4; ++i) {
      float4 w = make_float4(pacc[i][0], pacc[i][1], pacc[i][2], pacc[i][3]);
      *(float4*)(P + ((size_t)b * 512 + h * 64 + ty * 4 + i) * 512 + cc + tx * 4) = w;
    }
    __syncthreads();
  }
  // phase 5: u
  if (t < 64) {
    float a = 0.f;
    for (int e = 0; e < 64; ++e) a += att[t][e] * bvv[e];
    u[b * C_DIM + h * 64 + t] = a;
  }
}

// ---------- K3d: cvec_b = w_out @ u_b + b_out ----------
__global__ __launch_bounds__(256) void cvec_kernel(
    const float* __restrict__ w_out, const float* __restrict__ b_out,
    const float* __restrict__ u, float* __restrict__ cvec) {
  int b = blockIdx.x;
  __shared__ float us[512];
  int t = threadIdx.x;
  for (int i = t; i < 512; i += 256) us[i] = u[b * C_DIM + i];
  __syncthreads();
  for (int o = t; o < 512; o += 256) {
    const float* wr = w_out + (size_t)o * C_DIM;
    float a = 0.f;
    for (int r = 0; r < 512; ++r) a += wr[r] * us[r];
    cvec[b * C_DIM + o] = a + b_out[o];
  }
}

extern "C" void kernel_launch(void* const* d_in, const int* in_sizes, int n_in,
                              void* d_out, int out_size, void* d_ws, size_t ws_size,
                              hipStream_t stream) {
  const float* x     = (const float*)d_in[0];
  const float* gamma = (const float*)d_in[1];
  const float* beta  = (const float*)d_in[2];
  const float* w_qkv = (const float*)d_in[3];
  const float* b_qkv = (const float*)d_in[4];
  const float* w_out = (const float*)d_in[5];
  const float* b_out = (const float*)d_in[6];
  float* out = (float*)d_out;

  // workspace layout (~67.4 MB)
  double* chsum = (double*)d_ws;
  double* chsq  = chsum + BATCH * C_DIM;
  float* fb     = (float*)(chsq + BATCH * C_DIM);
  float* a_coef = fb;
  float* d_coef = a_coef + BATCH * C_DIM;
  float* svec   = d_coef + BATCH * C_DIM;
  float* uvec   = svec + BATCH * C_DIM;
  float* cvec   = uvec + BATCH * C_DIM;
  float* G      = cvec + BATCH * C_DIM;
  float* QG     = G  + (size_t)BATCH * C_DIM * C_DIM;
  float* P      = QG + (size_t)BATCH * C_DIM * C_DIM;
  float* Mw     = P  + (size_t)BATCH * C_DIM * C_DIM;

  channel_stats_kernel<<<BATCH * C_DIM, 256, 0, stream>>>(x, chsum, chsq);
  group_stats_kernel<<<BATCH * NGROUPS, 64, 0, stream>>>(chsum, chsq, gamma, beta,
                                                         a_coef, d_coef, svec);
  // G_b = h_b h_b^T
  gram_kernel<<<dim3(16, BATCH), 256, 0, stream>>>(x, a_coef, d_coef, G);
  // QG_b = Wq @ G_b
  nn_gemm_kernel<<<dim3(16, BATCH), 256, 0, stream>>>(
      w_qkv, 0, G, C_DIM * C_DIM, QG, C_DIM * C_DIM, C_DIM,
      nullptr, nullptr, nullptr, nullptr);
  // att/softmax + P_bh = att @ Wv_h, u
  attn_kernel<<<dim3(NHEADS, BATCH), 256, 0, stream>>>(QG, w_qkv, b_qkv, svec, P, uvec);
  // cvec_b = w_out @ u_b + b_out
  cvec_kernel<<<BATCH, 256, 0, stream>>>(w_out, b_out, uvec, cvec);
  // M_b = w_out @ P_b
  nn_gemm_kernel<<<dim3(16, BATCH), 256, 0, stream>>>(
      w_out, 0, P, C_DIM * C_DIM, Mw, C_DIM * C_DIM, C_DIM,
      nullptr, nullptr, nullptr, nullptr);
  // out = x + M_b @ h_b + cvec
  nn_gemm_kernel<<<dim3(4 * 32, BATCH), 256, 0, stream>>>(
      Mw, C_DIM * C_DIM, x, (long)C_DIM * N_DIM, out, (long)C_DIM * N_DIM, N_DIM,
      a_coef, d_coef, x, cvec);
}

// Round 2
// 624.169 us; speedup vs baseline: 2.5065x; 2.5065x over previous
//
#include <hip/hip_runtime.h>
#include <math.h>

#define C_DIM 512
#define N_DIM 4096
#define BATCH 16
#define NHEADS 8
#define NGROUPS 8

typedef __attribute__((ext_vector_type(8))) short bf16x8;
typedef __attribute__((ext_vector_type(4))) float f32x4;

#define MFMA16(a, b, c) __builtin_amdgcn_mfma_f32_16x16x32_bf16(a, b, c, 0, 0, 0)

__device__ __forceinline__ void gl16(const void* g, void* l) {
  __builtin_amdgcn_global_load_lds(
      (const __attribute__((address_space(1))) unsigned int*)g,
      (__attribute__((address_space(3))) unsigned int*)l, 16, 0, 0);
}

__device__ __forceinline__ unsigned f2bf_u(float f) {
  unsigned u = __float_as_uint(f);
  return (u + 0x7fffu + ((u >> 16) & 1u)) >> 16;  // RNE
}
__device__ __forceinline__ float bf2f(unsigned s) { return __uint_as_float(s << 16); }

// -------------------- K1: per-channel sums (double accum) --------------------
__global__ __launch_bounds__(256) void channel_stats_kernel(
    const float* __restrict__ x, double* __restrict__ chsum, double* __restrict__ chsq) {
  int bc = blockIdx.x;
  const float4* p = (const float4*)(x + (size_t)bc * N_DIM);
  double s = 0.0, ss = 0.0;
  for (int i = threadIdx.x; i < N_DIM / 4; i += 256) {
    float4 v = p[i];
    s  += (double)v.x + (double)v.y + (double)v.z + (double)v.w;
    ss += (double)v.x * v.x + (double)v.y * v.y + (double)v.z * v.z + (double)v.w * v.w;
  }
  __shared__ double rs[256], rss[256];
  int t = threadIdx.x;
  rs[t] = s; rss[t] = ss;
  __syncthreads();
  for (int o = 128; o > 0; o >>= 1) {
    if (t < o) { rs[t] += rs[t + o]; rss[t] += rss[t + o]; }
    __syncthreads();
  }
  if (t == 0) { chsum[bc] = rs[0]; chsq[bc] = rss[0]; }
}

// ---------- K1b: group stats -> per-(b,c) affine a,d and rowsum svec ----------
__global__ __launch_bounds__(64) void group_stats_kernel(
    const double* __restrict__ chsum, const double* __restrict__ chsq,
    const float* __restrict__ gamma, const float* __restrict__ beta,
    float* __restrict__ a_coef, float* __restrict__ d_coef, float* __restrict__ svec) {
  int b = blockIdx.x / NGROUPS, g = blockIdx.x % NGROUPS;
  int c = g * 64 + threadIdx.x;
  int idx = b * C_DIM + c;
  double cs = chsum[idx], cq = chsq[idx];
  double s = cs, ss = cq;
  for (int o = 32; o > 0; o >>= 1) { s += __shfl_xor(s, o, 64); ss += __shfl_xor(ss, o, 64); }
  const double M = 64.0 * 4096.0;
  double mean = s / M;
  double var = ss / M - mean * mean;
  double rstd = 1.0 / sqrt(var + 1e-5);
  double a = rstd * (double)gamma[c];
  double d = (double)beta[c] - mean * a;
  a_coef[idx] = (float)a;
  d_coef[idx] = (float)d;
  svec[idx] = (float)(a * cs + 4096.0 * d);
}

// ---------- weight prep: wq -> hi/lo bf16, wout -> bf16 ----------
__global__ __launch_bounds__(256) void wprep_kernel(
    const float* __restrict__ w_qkv, const float* __restrict__ w_out,
    unsigned short* __restrict__ wqhi, unsigned short* __restrict__ wqlo,
    unsigned short* __restrict__ woutb) {
  size_t e = ((size_t)blockIdx.x * 256 + threadIdx.x) * 4;
  float4 q = *(const float4*)(w_qkv + e);
  float qv[4] = {q.x, q.y, q.z, q.w};
  unsigned h[4], lo[4];
#pragma unroll
  for (int i = 0; i < 4; ++i) {
    h[i] = f2bf_u(qv[i]);
    lo[i] = f2bf_u(qv[i] - bf2f(h[i]));
  }
  uint2 ph, pl;
  ph.x = h[0] | (h[1] << 16); ph.y = h[2] | (h[3] << 16);
  pl.x = lo[0] | (lo[1] << 16); pl.y = lo[2] | (lo[3] << 16);
  *(uint2*)&wqhi[e] = ph;
  *(uint2*)&wqlo[e] = pl;
  float4 o = *(const float4*)(w_out + e);
  float ov[4] = {o.x, o.y, o.z, o.w};
  uint2 po;
  po.x = f2bf_u(ov[0]) | (f2bf_u(ov[1]) << 16);
  po.y = f2bf_u(ov[2]) | (f2bf_u(ov[3]) << 16);
  *(uint2*)&woutb[e] = po;
}

// -------------------- Gram (fused affine + hi/lo split, 3-pass MFMA) --------------------
// grid (16 tiles, 16 batch, 2 ksplit); Gp[ks*16+b][512][512] fp32
__global__ __launch_bounds__(256) void gram_fused_kernel(
    const float* __restrict__ x, const float* __restrict__ na,
    const float* __restrict__ nd, float* __restrict__ Gp) {
  int b = blockIdx.y, ks = blockIdx.z;
  int ti = blockIdx.x >> 2, tj = blockIdx.x & 3;
  int i0 = ti * 128, j0 = tj * 128;
  const float* xb = x + (size_t)b * C_DIM * N_DIM + (size_t)ks * 2048;
  __shared__ __align__(16) unsigned short As0[4096], As1[4096], Bs0[4096], Bs1[4096];
  int t = threadIdx.x, l = t & 63, w = t >> 6;
  int wr = w >> 1, wc = w & 1;
  int srow = t >> 1, scol = (t & 1) * 16;
  float aA = na[b * C_DIM + i0 + srow], dA = nd[b * C_DIM + i0 + srow];
  float aB = na[b * C_DIM + j0 + srow], dB = nd[b * C_DIM + j0 + srow];
  const float* pA = xb + (size_t)(i0 + srow) * N_DIM + scol;
  const float* pB = xb + (size_t)(j0 + srow) * N_DIM + scol;
  int swz = (srow & 7) << 4;
  int wb = srow * 64 + scol * 2;           // byte offset in plane
  int off0 = wb ^ swz, off1 = (wb + 16) ^ swz;
  f32x4 acc[4][4] = {};
  float4 fa0 = *(const float4*)(pA + 0), fa1 = *(const float4*)(pA + 4);
  float4 fa2 = *(const float4*)(pA + 8), fa3 = *(const float4*)(pA + 12);
  float4 fb0 = *(const float4*)(pB + 0), fb1 = *(const float4*)(pB + 4);
  float4 fb2 = *(const float4*)(pB + 8), fb3 = *(const float4*)(pB + 12);
  for (int kt = 0; kt < 2048; kt += 32) {
    __syncthreads();
    {
      float hv[16];
      const float4 fr[4] = {fa0, fa1, fa2, fa3};
#pragma unroll
      for (int q = 0; q < 4; ++q) {
        const float* f = (const float*)&fr[q];
#pragma unroll
        for (int e = 0; e < 4; ++e) hv[q * 4 + e] = aA * f[e] + dA;
      }
      bf16x8 h0, h1, l0, l1;
#pragma unroll
      for (int e = 0; e < 8; ++e) {
        unsigned u = f2bf_u(hv[e]); h0[e] = (short)u; l0[e] = (short)f2bf_u(hv[e] - bf2f(u));
        unsigned v = f2bf_u(hv[e + 8]); h1[e] = (short)v; l1[e] = (short)f2bf_u(hv[e + 8] - bf2f(v));
      }
      *(bf16x8*)((char*)As0 + off0) = h0; *(bf16x8*)((char*)As0 + off1) = h1;
      *(bf16x8*)((char*)As1 + off0) = l0; *(bf16x8*)((char*)As1 + off1) = l1;
    }
    {
      float hv[16];
      const float4 fr[4] = {fb0, fb1, fb2, fb3};
#pragma unroll
      for (int q = 0; q < 4; ++q) {
        const float* f = (const float*)&fr[q];
#pragma unroll
        for (int e = 0; e < 4; ++e) hv[q * 4 + e] = aB * f[e] + dB;
      }
      bf16x8 h0, h1, l0, l1;
#pragma unroll
      for (int e = 0; e < 8; ++e) {
        unsigned u = f2bf_u(hv[e]); h0[e] = (short)u; l0[e] = (short)f2bf_u(hv[e] - bf2f(u));
        unsigned v = f2bf_u(hv[e + 8]); h1[e] = (short)v; l1[e] = (short)f2bf_u(hv[e + 8] - bf2f(v));
      }
      *(bf16x8*)((char*)Bs0 + off0) = h0; *(bf16x8*)((char*)Bs0 + off1) = h1;
      *(bf16x8*)((char*)Bs1 + off0) = l0; *(bf16x8*)((char*)Bs1 + off1) = l1;
    }
    if (kt + 32 < 2048) {  // prefetch next
      fa0 = *(const float4*)(pA + kt + 32); fa1 = *(const float4*)(pA + kt + 36);
      fa2 = *(const float4*)(pA + kt + 40); fa3 = *(const float4*)(pA + kt + 44);
      fb0 = *(const float4*)(pB + kt + 32); fb1 = *(const float4*)(pB + kt + 36);
      fb2 = *(const float4*)(pB + kt + 40); fb3 = *(const float4*)(pB + kt + 44);
    }
    __syncthreads();
    bf16x8 ah[4], al[4], bh[4], bl[4];
#pragma unroll
    for (int m = 0; m < 4; ++m) {
      int row = wr * 64 + m * 16 + (l & 15);
      int off = (row * 64 + (l >> 4) * 16) ^ ((row & 7) << 4);
      ah[m] = *(const bf16x8*)((const char*)As0 + off);
      al[m] = *(const bf16x8*)((const char*)As1 + off);
    }
#pragma unroll
    for (int n = 0; n < 4; ++n) {
      int row = wc * 64 + n * 16 + (l & 15);
      int off = (row * 64 + (l >> 4) * 16) ^ ((row & 7) << 4);
      bh[n] = *(const bf16x8*)((const char*)Bs0 + off);
      bl[n] = *(const bf16x8*)((const char*)Bs1 + off);
    }
#pragma unroll
    for (int m = 0; m < 4; ++m)
#pragma unroll
      for (int n = 0; n < 4; ++n) {
        acc[m][n] = MFMA16(ah[m], bh[n], acc[m][n]);
        acc[m][n] = MFMA16(ah[m], bl[n], acc[m][n]);
        acc[m][n] = MFMA16(al[m], bh[n], acc[m][n]);
      }
  }
  float* Cb = Gp + ((size_t)(ks * 16 + b)) * C_DIM * C_DIM;
#pragma unroll
  for (int m = 0; m < 4; ++m) {
    int rb = i0 + wr * 64 + m * 16 + (l >> 4) * 4;
#pragma unroll
    for (int n = 0; n < 4; ++n) {
      int col = j0 + wc * 64 + n * 16 + (l & 15);
#pragma unroll
      for (int j = 0; j < 4; ++j)
        Cb[(size_t)(rb + j) * C_DIM + col] = acc[m][n][j];
    }
  }
}

// ---------- gsum: Ghi/Glo <- split(Gp[0] + Gp[1]) ----------
__global__ __launch_bounds__(256) void gsum_kernel(
    const float* __restrict__ G0, const float* __restrict__ G1,
    unsigned short* __restrict__ Ghi, unsigned short* __restrict__ Glo) {
  size_t i = ((size_t)blockIdx.x * 256 + threadIdx.x) * 4;
  float4 a = *(const float4*)(G0 + i);
  float4 b = *(const float4*)(G1 + i);
  float v[4] = {a.x + b.x, a.y + b.y, a.z + b.z, a.w + b.w};
  unsigned h[4], lo[4];
#pragma unroll
  for (int e = 0; e < 4; ++e) {
    h[e] = f2bf_u(v[e]);
    lo[e] = f2bf_u(v[e] - bf2f(h[e]));
  }
  uint2 ph, pl;
  ph.x = h[0] | (h[1] << 16); ph.y = h[2] | (h[3] << 16);
  pl.x = lo[0] | (lo[1] << 16); pl.y = lo[2] | (lo[3] << 16);
  *(uint2*)&Ghi[i] = ph;
  *(uint2*)&Glo[i] = pl;
}

// ---------- pure NT GEMM, hi/lo 3-pass: C = A @ B^T (both [row][K] bf16) ----------
__global__ __launch_bounds__(256) void gemm_nt_split3_kernel(
    const unsigned short* __restrict__ Ahi, const unsigned short* __restrict__ Alo,
    long sAb, int lda,
    const unsigned short* __restrict__ Bhi, const unsigned short* __restrict__ Blo,
    long sBb, int ldb,
    float* __restrict__ Cout, long sCb, int ldc, int ntj, int K) {
  int b = blockIdx.y;
  int ti = blockIdx.x / ntj, tj = blockIdx.x % ntj;
  int i0 = ti * 128, j0 = tj * 128;
  const unsigned short* Ah = Ahi + (size_t)b * sAb;
  const unsigned short* Al = Alo + (size_t)b * sAb;
  const unsigned short* Bh = Bhi + (size_t)b * sBb;
  const unsigned short* Bl = Blo + (size_t)b * sBb;
  float* Cb = Cout + (size_t)b * sCb;
  __shared__ __align__(16) unsigned short As[8192], Bs[8192];  // 2 planes each
  int t = threadIdx.x, l = t & 63, w = t >> 6;
  int wr = w >> 1, wc = w & 1;
  int r0 = t >> 2, ce = (t & 3) * 8;
  f32x4 acc[4][4] = {};
  for (int kt = 0; kt < K; kt += 32) {
    __syncthreads();
    gl16(Ah + (size_t)(i0 + r0) * lda + kt + ce, (char*)As + t * 16);
    gl16(Ah + (size_t)(i0 + 64 + r0) * lda + kt + ce, (char*)As + 4096 + t * 16);
    gl16(Al + (size_t)(i0 + r0) * lda + kt + ce, (char*)As + 8192 + t * 16);
    gl16(Al + (size_t)(i0 + 64 + r0) * lda + kt + ce, (char*)As + 12288 + t * 16);
    gl16(Bh + (size_t)(j0 + r0) * ldb + kt + ce, (char*)Bs + t * 16);
    gl16(Bh + (size_t)(j0 + 64 + r0) * ldb + kt + ce, (char*)Bs + 4096 + t * 16);
    gl16(Bl + (size_t)(j0 + r0) * ldb + kt + ce, (char*)Bs + 8192 + t * 16);
    gl16(Bl + (size_t)(j0 + 64 + r0) * ldb + kt + ce, (char*)Bs + 12288 + t * 16);
    __syncthreads();
    bf16x8 ah[4], al4[4], bh[4], bl4[4];
#pragma unroll
    for (int m = 0; m < 4; ++m) {
      int row = wr * 64 + m * 16 + (l & 15);
      int off = row * 64 + (l >> 4) * 16;
      ah[m] = *(const bf16x8*)((const char*)As + off);
      al4[m] = *(const bf16x8*)((const char*)As + 8192 + off);
    }
#pragma unroll
    for (int n = 0; n < 4; ++n) {
      int row = wc * 64 + n * 16 + (l & 15);
      int off = row * 64 + (l >> 4) * 16;
      bh[n] = *(const bf16x8*)((const char*)Bs + off);
      bl4[n] = *(const bf16x8*)((const char*)Bs + 8192 + off);
    }
#pragma unroll
    for (int m = 0; m < 4; ++m)
#pragma unroll
      for (int n = 0; n < 4; ++n) {
        acc[m][n] = MFMA16(ah[m], bh[n], acc[m][n]);
        acc[m][n] = MFMA16(ah[m], bl4[n], acc[m][n]);
        acc[m][n] = MFMA16(al4[m], bh[n], acc[m][n]);
      }
  }
#pragma unroll
  for (int m = 0; m < 4; ++m) {
    int rb = i0 + wr * 64 + m * 16 + (l >> 4) * 4;
#pragma unroll
    for (int n = 0; n < 4; ++n) {
      int col = j0 + wc * 64 + n * 16 + (l & 15);
#pragma unroll
      for (int j = 0; j < 4; ++j)
        Cb[(size_t)(rb + j) * ldc + col] = acc[m][n][j];
    }
  }
}

// ---------- pure NT GEMM single bf16, bf16 output: C = A @ B^T ----------
__global__ __launch_bounds__(256) void gemm_nt_bf16_kernel(
    const unsigned short* __restrict__ A, long sAb, int lda,
    const unsigned short* __restrict__ B, long sBb, int ldb,
    unsigned short* __restrict__ outB, long sCb, int ldc, int ntj, int K) {
  int b = blockIdx.y;
  int ti = blockIdx.x / ntj, tj = blockIdx.x % ntj;
  int i0 = ti * 128, j0 = tj * 128;
  const unsigned short* Ab = A + (size_t)b * sAb;
  const unsigned short* Bb = B + (size_t)b * sBb;
  __shared__ __align__(16) unsigned short As[4096], Bs[4096];
  int t = threadIdx.x, l = t & 63, w = t >> 6;
  int wr = w >> 1, wc = w & 1;
  int r0 = t >> 2, ce = (t & 3) * 8;
  f32x4 acc[4][4] = {};
  for (int kt = 0; kt < K; kt += 32) {
    __syncthreads();
    gl16(Ab + (size_t)(i0 + r0) * lda + kt + ce, (char*)As + t * 16);
    gl16(Ab + (size_t)(i0 + 64 + r0) * lda + kt + ce, (char*)As + 4096 + t * 16);
    gl16(Bb + (size_t)(j0 + r0) * ldb + kt + ce, (char*)Bs + t * 16);
    gl16(Bb + (size_t)(j0 + 64 + r0) * ldb + kt + ce, (char*)Bs + 4096 + t * 16);
    __syncthreads();
    bf16x8 ah[4], bh[4];
#pragma unroll
    for (int m = 0; m < 4; ++m) {
      int row = wr * 64 + m * 16 + (l & 15);
      ah[m] = *(const bf16x8*)((const char*)As + row * 64 + (l >> 4) * 16);
    }
#pragma unroll
    for (int n = 0; n < 4; ++n) {
      int row = wc * 64 + n * 16 + (l & 15);
      bh[n] = *(const bf16x8*)((const char*)Bs + row * 64 + (l >> 4) * 16);
    }
#pragma unroll
    for (int m = 0; m < 4; ++m)
#pragma unroll
      for (int n = 0; n < 4; ++n)
        acc[m][n] = MFMA16(ah[m], bh[n], acc[m][n]);
  }
  unsigned short* Ob = outB + (size_t)b * sCb;
#pragma unroll
  for (int m = 0; m < 4; ++m) {
    int rb = i0 + wr * 64 + m * 16 + (l >> 4) * 4;
#pragma unroll
    for (int n = 0; n < 4; ++n) {
      int col = j0 + wc * 64 + n * 16 + (l & 15);
#pragma unroll
      for (int j = 0; j < 4; ++j)
        Ob[(size_t)(rb + j) * ldc + col] = (unsigned short)f2bf_u(acc[m][n][j]);
    }
  }
}

// ---------- attention per (b,h): S = QG.Wk^T + bias; softmax; Pt = (att @ Wv)^T ----------
__global__ __launch_bounds__(256) void attn_kernel(
    const float* __restrict__ QG, const float* __restrict__ w_qkv,
    const float* __restrict__ b_qkv, const float* __restrict__ svec,
    unsigned short* __restrict__ Pt, float* __restrict__ u) {
  int h = blockIdx.x, b = blockIdx.y;
  __shared__ float s_sh[512];
  __shared__ float qs[64], ks[64], bqv[64], bkv[64], bvv[64];
  __shared__ float pool[4096];
  __shared__ float att[64][66];
  int t = threadIdx.x, tx = t & 15, ty = t >> 4;
  for (int i = t; i < 512; i += 256) s_sh[i] = svec[b * C_DIM + i];
  if (t < 64) {
    bqv[t] = b_qkv[h * 64 + t];
    bkv[t] = b_qkv[512 + h * 64 + t];
    bvv[t] = b_qkv[1024 + h * 64 + t];
  }
  __syncthreads();
  if (t < 64) {
    const float* wr = w_qkv + (size_t)(h * 64 + t) * C_DIM;
    float a = 0.f;
    for (int c = 0; c < 512; ++c) a += wr[c] * s_sh[c];
    qs[t] = a;
  } else if (t < 128) {
    int e = t - 64;
    const float* wr = w_qkv + (size_t)(512 + h * 64 + e) * C_DIM;
    float a = 0.f;
    for (int c = 0; c < 512; ++c) a += wr[c] * s_sh[c];
    ks[e] = a;
  }
  __syncthreads();
  float acc[4][4] = {};
  float* As = pool;
  float* Bs = pool + 2048;
  for (int kt = 0; kt < 512; kt += 32) {
#pragma unroll
    for (int r = 0; r < 2; ++r) {
      int idx = t + r * 256;
      int row = idx >> 3, c4 = (idx & 7) * 4;
      float4 va = *(const float4*)(QG + ((size_t)b * 512 + h * 64 + row) * 512 + kt + c4);
      As[(c4 + 0) * 64 + row] = va.x; As[(c4 + 1) * 64 + row] = va.y;
      As[(c4 + 2) * 64 + row] = va.z; As[(c4 + 3) * 64 + row] = va.w;
      float4 vb = *(const float4*)(w_qkv + (size_t)(512 + h * 64 + row) * 512 + kt + c4);
      Bs[(c4 + 0) * 64 + row] = vb.x; Bs[(c4 + 1) * 64 + row] = vb.y;
      Bs[(c4 + 2) * 64 + row] = vb.z; Bs[(c4 + 3) * 64 + row] = vb.w;
    }
    __syncthreads();
#pragma unroll 4
    for (int k = 0; k < 32; ++k) {
      float4 a4 = *(const float4*)&As[k * 64 + ty * 4];
      float4 b4 = *(const float4*)&Bs[k * 64 + tx * 4];
      float ar[4] = {a4.x, a4.y, a4.z, a4.w};
      float br[4] = {b4.x, b4.y, b4.z, b4.w};
#pragma unroll
      for (int i = 0; i < 4; ++i)
#pragma unroll
        for (int j = 0; j < 4; ++j) acc[i][j] += ar[i] * br[j];
    }
    __syncthreads();
  }
#pragma unroll
  for (int i = 0; i < 4; ++i) {
    int d = ty * 4 + i;
#pragma unroll
    for (int j = 0; j < 4; ++j) {
      int e = tx * 4 + j;
      float raw = acc[i][j] + bqv[d] * ks[e] + bkv[e] * qs[d] + 4096.0f * bqv[d] * bkv[e];
      att[d][e] = raw * 0.125f;
    }
  }
  __syncthreads();
  if (t < 64) {
    float m = -1e30f;
    for (int e = 0; e < 64; ++e) m = fmaxf(m, att[t][e]);
    float ssum = 0.f;
    for (int e = 0; e < 64; ++e) { float p = expf(att[t][e] - m); att[t][e] = p; ssum += p; }
    float inv = 1.0f / ssum;
    for (int e = 0; e < 64; ++e) att[t][e] *= inv;
  }
  __syncthreads();
  float* Ws = pool;
  for (int cc = 0; cc < 512; cc += 64) {
#pragma unroll
    for (int r = 0; r < 4; ++r) {
      int idx = t + r * 256;
      int row = idx >> 4, c4 = (idx & 15) * 4;
      *(float4*)&Ws[row * 64 + c4] =
          *(const float4*)(w_qkv + (size_t)(1024 + h * 64 + row) * 512 + cc + c4);
    }
    __syncthreads();
    float pacc[4][4] = {};
#pragma unroll 4
    for (int e = 0; e < 64; ++e) {
      float a0 = att[ty * 4 + 0][e], a1 = att[ty * 4 + 1][e];
      float a2 = att[ty * 4 + 2][e], a3 = att[ty * 4 + 3][e];
      float4 b4 = *(const float4*)&Ws[e * 64 + tx * 4];
      float br[4] = {b4.x, b4.y, b4.z, b4.w};
#pragma unroll
      for (int j = 0; j < 4; ++j) {
        pacc[0][j] += a0 * br[j]; pacc[1][j] += a1 * br[j];
        pacc[2][j] += a2 * br[j]; pacc[3][j] += a3 * br[j];
      }
    }
    // Pt[b][c][r] = P[r][c]  (bf16)
#pragma unroll
    for (int j = 0; j < 4; ++j) {
      uint2 pk;
      pk.x = f2bf_u(pacc[0][j]) | (f2bf_u(pacc[1][j]) << 16);
      pk.y = f2bf_u(pacc[2][j]) | (f2bf_u(pacc[3][j]) << 16);
      *(uint2*)&Pt[((size_t)b * 512 + cc + tx * 4 + j) * 512 + h * 64 + ty * 4] = pk;
    }
    __syncthreads();
  }
  if (t < 64) {
    float a = 0.f;
    for (int e = 0; e < 64; ++e) a += att[t][e] * bvv[e];
    u[b * C_DIM + h * 64 + t] = a;
  }
}

// ---------- cvec_b = w_out @ u_b + b_out ----------
__global__ __launch_bounds__(256) void cvec_kernel(
    const float* __restrict__ w_out, const float* __restrict__ b_out,
    const float* __restrict__ u, float* __restrict__ cvec) {
  int b = blockIdx.x;
  __shared__ float us[512];
  int t = threadIdx.x;
  for (int i = t; i < 512; i += 256) us[i] = u[b * C_DIM + i];
  __syncthreads();
  for (int o = t; o < 512; o += 256) {
    const float* wr = w_out + (size_t)o * C_DIM;
    float a = 0.f;
    for (int r = 0; r < 512; ++r) a += wr[r] * us[r];
    cvec[b * C_DIM + o] = a + b_out[o];
  }
}

// ---------- final fused: out = x + M @ h + cvec   (A=Mbf gl16; B from x, transposed) ----------
// grid (4*32 tiles, 16 batch)
__global__ __launch_bounds__(256) void final_fused_kernel(
    const unsigned short* __restrict__ Mbf, const float* __restrict__ x,
    const float* __restrict__ na, const float* __restrict__ nd,
    const float* __restrict__ cvec, float* __restrict__ out) {
  int b = blockIdx.y;
  int ti = blockIdx.x >> 5, tj = blockIdx.x & 31;
  int i0 = ti * 128, n0 = tj * 128;
  const unsigned short* Mb = Mbf + (size_t)b * 512 * 512;
  const float* xb = x + (size_t)b * C_DIM * N_DIM;
  float* ob = out + (size_t)b * C_DIM * N_DIM;
  __shared__ __align__(16) unsigned short As[4096], Bs[4096];
  int t = threadIdx.x, l = t & 63, w = t >> 6;
  int wr = w >> 1, wc = w & 1;
  int r0 = t >> 2, ce = (t & 3) * 8;
  int c0 = (t >> 5) * 4, n4 = (t & 31) * 4;
  f32x4 acc[4][4] = {};
  float4 q0, q1, q2, q3;
  q0 = *(const float4*)(xb + (size_t)(c0 + 0) * N_DIM + n0 + n4);
  q1 = *(const float4*)(xb + (size_t)(c0 + 1) * N_DIM + n0 + n4);
  q2 = *(const float4*)(xb + (size_t)(c0 + 2) * N_DIM + n0 + n4);
  q3 = *(const float4*)(xb + (size_t)(c0 + 3) * N_DIM + n0 + n4);
  for (int kt = 0; kt < 512; kt += 32) {
    __syncthreads();
    gl16(Mb + (size_t)(i0 + r0) * 512 + kt + ce, (char*)As + t * 16);
    gl16(Mb + (size_t)(i0 + 64 + r0) * 512 + kt + ce, (char*)As + 4096 + t * 16);
    {
      float ac[4], dc[4];
#pragma unroll
      for (int cc = 0; cc < 4; ++cc) {
        ac[cc] = na[b * C_DIM + kt + c0 + cc];
        dc[cc] = nd[b * C_DIM + kt + c0 + cc];
      }
      const float* f0 = (const float*)&q0;
      const float* f1 = (const float*)&q1;
      const float* f2 = (const float*)&q2;
      const float* f3 = (const float*)&q3;
#pragma unroll
      for (int e = 0; e < 4; ++e) {
        int n = n4 + e;
        unsigned b0 = f2bf_u(ac[0] * f0[e] + dc[0]);
        unsigned b1 = f2bf_u(ac[1] * f1[e] + dc[1]);
        unsigned b2 = f2bf_u(ac[2] * f2[e] + dc[2]);
        unsigned b3 = f2bf_u(ac[3] * f3[e] + dc[3]);
        uint2 pk; pk.x = b0 | (b1 << 16); pk.y = b2 | (b3 << 16);
        int off = (n * 64 + c0 * 2) ^ ((n & 7) << 4);
        *(uint2*)((char*)Bs + off) = pk;
      }
    }
    if (kt + 32 < 512) {
      q0 = *(const float4*)(xb + (size_t)(kt + 32 + c0 + 0) * N_DIM + n0 + n4);
      q1 = *(const float4*)(xb + (size_t)(kt + 32 + c0 + 1) * N_DIM + n0 + n4);
      q2 = *(const float4*)(xb + (size_t)(kt + 32 + c0 + 2) * N_DIM + n0 + n4);
      q3 = *(const float4*)(xb + (size_t)(kt + 32 + c0 + 3) * N_DIM + n0 + n4);
    }
    __syncthreads();
    bf16x8 ah[4], bh[4];
#pragma unroll
    for (int m = 0; m < 4; ++m) {
      int row = wr * 64 + m * 16 + (l & 15);
      ah[m] = *(const bf16x8*)((const char*)As + row * 64 + (l >> 4) * 16);
    }
#pragma unroll
    for (int n = 0; n < 4; ++n) {
      int row = wc * 64 + n * 16 + (l & 15);
      int off = (row * 64 + (l >> 4) * 16) ^ ((row & 7) << 4);
      bh[n] = *(const bf16x8*)((const char*)Bs + off);
    }
#pragma unroll
    for (int m = 0; m < 4; ++m)
#pragma unroll
      for (int n = 0; n < 4; ++n)
        acc[m][n] = MFMA16(ah[m], bh[n], acc[m][n]);
  }
#pragma unroll
  for (int m = 0; m < 4; ++m) {
    int rb = i0 + wr * 64 + m * 16 + (l >> 4) * 4;
#pragma unroll
    for (int n = 0; n < 4; ++n) {
      int col = n0 + wc * 64 + n * 16 + (l & 15);
#pragma unroll
      for (int j = 0; j < 4; ++j) {
        size_t off = (size_t)(rb + j) * N_DIM + col;
        ob[off] = acc[m][n][j] + xb[off] + cvec[b * C_DIM + rb + j];
      }
    }
  }
}

extern "C" void kernel_launch(void* const* d_in, const int* in_sizes, int n_in,
                              void* d_out, int out_size, void* d_ws, size_t ws_size,
                              hipStream_t stream) {
  const float* x     = (const float*)d_in[0];
  const float* gamma = (const float*)d_in[1];
  const float* beta  = (const float*)d_in[2];
  const float* w_qkv = (const float*)d_in[3];
  const float* b_qkv = (const float*)d_in[4];
  const float* w_out = (const float*)d_in[5];
  const float* b_out = (const float*)d_in[6];
  float* out = (float*)d_out;

  char* wp = (char*)d_ws;
  double* chsum = (double*)wp; wp += 8192 * 8;
  double* chsq  = (double*)wp; wp += 8192 * 8;
  float* a_coef = (float*)wp; wp += 8192 * 4;
  float* d_coef = (float*)wp; wp += 8192 * 4;
  float* svec   = (float*)wp; wp += 8192 * 4;
  float* uvec   = (float*)wp; wp += 8192 * 4;
  float* cvec   = (float*)wp; wp += 8192 * 4;
  unsigned short* wqhi  = (unsigned short*)wp; wp += 262144 * 2;
  unsigned short* wqlo  = (unsigned short*)wp; wp += 262144 * 2;
  unsigned short* woutb = (unsigned short*)wp; wp += 262144 * 2;
  float* Gp = (float*)wp; wp += (size_t)2 * 16 * 512 * 512 * 4;   // 33.55 MB
  unsigned short* Ghi = (unsigned short*)wp; wp += (size_t)16 * 512 * 512 * 2;
  unsigned short* Glo = (unsigned short*)wp; wp += (size_t)16 * 512 * 512 * 2;
  // aliases (liveness-disjoint)
  float* QG = Gp;                                                  // after gsum
  unsigned short* Pt = (unsigned short*)(Gp + (size_t)16 * 512 * 512);
  unsigned short* Mbf = Ghi;                                       // after QG-GEMM

  channel_stats_kernel<<<BATCH * C_DIM, 256, 0, stream>>>(x, chsum, chsq);
  group_stats_kernel<<<BATCH * NGROUPS, 64, 0, stream>>>(chsum, chsq, gamma, beta,
                                                         a_coef, d_coef, svec);
  wprep_kernel<<<256, 256, 0, stream>>>(w_qkv, w_out, wqhi, wqlo, woutb);
  // G partials (ksplit=2)
  gram_fused_kernel<<<dim3(16, BATCH, 2), 256, 0, stream>>>(x, a_coef, d_coef, Gp);
  gsum_kernel<<<4096, 256, 0, stream>>>(Gp, Gp + (size_t)16 * 512 * 512, Ghi, Glo);
  // QG = Wq @ G  (G symmetric -> NT with B rows = G rows), 3-pass hi/lo
  gemm_nt_split3_kernel<<<dim3(16, BATCH), 256, 0, stream>>>(
      wqhi, wqlo, 0, 512, Ghi, Glo, 512 * 512, 512, QG, 512 * 512, 512, 4, 512);
  attn_kernel<<<dim3(NHEADS, BATCH), 256, 0, stream>>>(QG, w_qkv, b_qkv, svec, Pt, uvec);
  cvec_kernel<<<BATCH, 256, 0, stream>>>(w_out, b_out, uvec, cvec);
  // M = Wout @ P  == NT(A=Wout[o][r], B=Pt[c][r]); bf16 out
  gemm_nt_bf16_kernel<<<dim3(16, BATCH), 256, 0, stream>>>(
      woutb, 0, 512, Pt, 512 * 512, 512, Mbf, 512 * 512, 512, 4, 512);
  // out = x + M @ h + cvec
  final_fused_kernel<<<dim3(128, BATCH), 256, 0, stream>>>(Mbf, x, a_coef, d_coef, cvec, out);
}

// Round 7
// 590.810 us; speedup vs baseline: 2.6480x; 1.0565x over previous
//
#include <hip/hip_runtime.h>
#include <math.h>

#define C_DIM 512
#define N_DIM 4096
#define BATCH 16
#define NHEADS 8
#define NGROUPS 8

typedef __attribute__((ext_vector_type(8))) short bf16x8;
typedef __attribute__((ext_vector_type(4))) float f32x4;
typedef unsigned short u16;

#define MFMA16(a, b, c) __builtin_amdgcn_mfma_f32_16x16x32_bf16(a, b, c, 0, 0, 0)

__device__ __forceinline__ void gl16(const void* g, void* l) {
  __builtin_amdgcn_global_load_lds(
      (const __attribute__((address_space(1))) unsigned int*)g,
      (__attribute__((address_space(3))) unsigned int*)l, 16, 0, 0);
}

__device__ __forceinline__ unsigned f2bf_u(float f) {
  unsigned u = __float_as_uint(f);
  return (u + 0x7fffu + ((u >> 16) & 1u)) >> 16;  // RNE
}
__device__ __forceinline__ float bf2f(unsigned s) { return __uint_as_float(s << 16); }

// -------------------- K1: per-channel sums (double accum) --------------------
__global__ __launch_bounds__(256) void channel_stats_kernel(
    const float* __restrict__ x, double* __restrict__ chsum, double* __restrict__ chsq) {
  int bc = blockIdx.x;
  const float4* p = (const float4*)(x + (size_t)bc * N_DIM);
  double s = 0.0, ss = 0.0;
  for (int i = threadIdx.x; i < N_DIM / 4; i += 256) {
    float4 v = p[i];
    s  += (double)v.x + (double)v.y + (double)v.z + (double)v.w;
    ss += (double)v.x * v.x + (double)v.y * v.y + (double)v.z * v.z + (double)v.w * v.w;
  }
  __shared__ double rs[256], rss[256];
  int t = threadIdx.x;
  rs[t] = s; rss[t] = ss;
  __syncthreads();
  for (int o = 128; o > 0; o >>= 1) {
    if (t < o) { rs[t] += rs[t + o]; rss[t] += rss[t + o]; }
    __syncthreads();
  }
  if (t == 0) { chsum[bc] = rs[0]; chsq[bc] = rss[0]; }
}

// ---------- K1b: group stats -> per-(b,c) affine coef a,d and rowsum s ----------
__global__ __launch_bounds__(64) void group_stats_kernel(
    const double* __restrict__ chsum, const double* __restrict__ chsq,
    const float* __restrict__ gamma, const float* __restrict__ beta,
    float* __restrict__ a_coef, float* __restrict__ d_coef, float* __restrict__ svec) {
  int b = blockIdx.x / NGROUPS, g = blockIdx.x % NGROUPS;
  int c = g * 64 + threadIdx.x;
  int idx = b * C_DIM + c;
  double cs = chsum[idx], cq = chsq[idx];
  double s = cs, ss = cq;
  for (int o = 32; o > 0; o >>= 1) { s += __shfl_xor(s, o, 64); ss += __shfl_xor(ss, o, 64); }
  const double M = 64.0 * 4096.0;
  double mean = s / M;
  double var = ss / M - mean * mean;
  double rstd = 1.0 / sqrt(var + 1e-5);
  double a = rstd * (double)gamma[c];
  double d = (double)beta[c] - mean * a;
  a_coef[idx] = (float)a;
  d_coef[idx] = (float)d;
  svec[idx] = (float)(a * cs + 4096.0 * d);
}

// ---------- weight prep: wq -> bf16, wout -> bf16 ----------
__global__ __launch_bounds__(256) void wprep_kernel(
    const float* __restrict__ w_qkv, const float* __restrict__ w_out,
    u16* __restrict__ wqb, u16* __restrict__ woutb) {
  size_t e = ((size_t)blockIdx.x * 256 + threadIdx.x) * 4;
  float4 q = *(const float4*)(w_qkv + e);
  uint2 ph;
  ph.x = f2bf_u(q.x) | (f2bf_u(q.y) << 16);
  ph.y = f2bf_u(q.z) | (f2bf_u(q.w) << 16);
  *(uint2*)&wqb[e] = ph;
  float4 o = *(const float4*)(w_out + e);
  uint2 po;
  po.x = f2bf_u(o.x) | (f2bf_u(o.y) << 16);
  po.y = f2bf_u(o.z) | (f2bf_u(o.w) << 16);
  *(uint2*)&woutb[e] = po;
}

// -------------------- Gram (fused affine, single-pass bf16 MFMA) --------------------
// grid (16 tiles, 16 batch, 2 ksplit); Gp[ks*16+b][512][512] fp32
__global__ __launch_bounds__(256) void gram_fused_kernel(
    const float* __restrict__ x, const float* __restrict__ na,
    const float* __restrict__ nd, float* __restrict__ Gp) {
  int b = blockIdx.y, ks = blockIdx.z;
  int ti = blockIdx.x >> 2, tj = blockIdx.x & 3;
  int i0 = ti * 128, j0 = tj * 128;
  const float* xb = x + (size_t)b * C_DIM * N_DIM + (size_t)ks * 2048;
  __shared__ __align__(16) u16 As0[4096], Bs0[4096];
  int t = threadIdx.x, l = t & 63, w = t >> 6;
  int wr = w >> 1, wc = w & 1;
  int srow = t >> 1, scol = (t & 1) * 16;
  float aA = na[b * C_DIM + i0 + srow], dA = nd[b * C_DIM + i0 + srow];
  float aB = na[b * C_DIM + j0 + srow], dB = nd[b * C_DIM + j0 + srow];
  const float* pA = xb + (size_t)(i0 + srow) * N_DIM + scol;
  const float* pB = xb + (size_t)(j0 + srow) * N_DIM + scol;
  int swz = (srow & 7) << 4;
  int wb = srow * 64 + scol * 2;           // byte offset in plane
  int off0 = wb ^ swz, off1 = (wb + 16) ^ swz;
  f32x4 acc[4][4] = {};
  float4 fa0 = *(const float4*)(pA + 0), fa1 = *(const float4*)(pA + 4);
  float4 fa2 = *(const float4*)(pA + 8), fa3 = *(const float4*)(pA + 12);
  float4 fb0 = *(const float4*)(pB + 0), fb1 = *(const float4*)(pB + 4);
  float4 fb2 = *(const float4*)(pB + 8), fb3 = *(const float4*)(pB + 12);
  for (int kt = 0; kt < 2048; kt += 32) {
    __syncthreads();
    {
      float hv[16];
      const float4 fr[4] = {fa0, fa1, fa2, fa3};
#pragma unroll
      for (int q = 0; q < 4; ++q) {
        const float* f = (const float*)&fr[q];
#pragma unroll
        for (int e = 0; e < 4; ++e) hv[q * 4 + e] = aA * f[e] + dA;
      }
      bf16x8 h0, h1;
#pragma unroll
      for (int e = 0; e < 8; ++e) {
        h0[e] = (short)f2bf_u(hv[e]);
        h1[e] = (short)f2bf_u(hv[e + 8]);
      }
      *(bf16x8*)((char*)As0 + off0) = h0; *(bf16x8*)((char*)As0 + off1) = h1;
    }
    {
      float hv[16];
      const float4 fr[4] = {fb0, fb1, fb2, fb3};
#pragma unroll
      for (int q = 0; q < 4; ++q) {
        const float* f = (const float*)&fr[q];
#pragma unroll
        for (int e = 0; e < 4; ++e) hv[q * 4 + e] = aB * f[e] + dB;
      }
      bf16x8 h0, h1;
#pragma unroll
      for (int e = 0; e < 8; ++e) {
        h0[e] = (short)f2bf_u(hv[e]);
        h1[e] = (short)f2bf_u(hv[e + 8]);
      }
      *(bf16x8*)((char*)Bs0 + off0) = h0; *(bf16x8*)((char*)Bs0 + off1) = h1;
    }
    if (kt + 32 < 2048) {  // prefetch next
      fa0 = *(const float4*)(pA + kt + 32); fa1 = *(const float4*)(pA + kt + 36);
      fa2 = *(const float4*)(pA + kt + 40); fa3 = *(const float4*)(pA + kt + 44);
      fb0 = *(const float4*)(pB + kt + 32); fb1 = *(const float4*)(pB + kt + 36);
      fb2 = *(const float4*)(pB + kt + 40); fb3 = *(const float4*)(pB + kt + 44);
    }
    __syncthreads();
    bf16x8 ah[4], bh[4];
#pragma unroll
    for (int m = 0; m < 4; ++m) {
      int row = wr * 64 + m * 16 + (l & 15);
      int off = (row * 64 + (l >> 4) * 16) ^ ((row & 7) << 4);
      ah[m] = *(const bf16x8*)((const char*)As0 + off);
    }
#pragma unroll
    for (int n = 0; n < 4; ++n) {
      int row = wc * 64 + n * 16 + (l & 15);
      int off = (row * 64 + (l >> 4) * 16) ^ ((row & 7) << 4);
      bh[n] = *(const bf16x8*)((const char*)Bs0 + off);
    }
#pragma unroll
    for (int m = 0; m < 4; ++m)
#pragma unroll
      for (int n = 0; n < 4; ++n)
        acc[m][n] = MFMA16(ah[m], bh[n], acc[m][n]);
  }
  float* Cb = Gp + ((size_t)(ks * 16 + b)) * C_DIM * C_DIM;
#pragma unroll
  for (int m = 0; m < 4; ++m) {
    int rb = i0 + wr * 64 + m * 16 + (l >> 4) * 4;
#pragma unroll
    for (int n = 0; n < 4; ++n) {
      int col = j0 + wc * 64 + n * 16 + (l & 15);
#pragma unroll
      for (int j = 0; j < 4; ++j)
        Cb[(size_t)(rb + j) * C_DIM + col] = acc[m][n][j];
    }
  }
}

// ---------- gsum: Ghi <- bf16(Gp[0] + Gp[1]) ----------
__global__ __launch_bounds__(256) void gsum_kernel(
    const float* __restrict__ G0, const float* __restrict__ G1,
    u16* __restrict__ Ghi) {
  size_t i = ((size_t)blockIdx.x * 256 + threadIdx.x) * 4;
  float4 a = *(const float4*)(G0 + i);
  float4 b = *(const float4*)(G1 + i);
  uint2 ph;
  ph.x = f2bf_u(a.x + b.x) | (f2bf_u(a.y + b.y) << 16);
  ph.y = f2bf_u(a.z + b.z) | (f2bf_u(a.w + b.w) << 16);
  *(uint2*)&Ghi[i] = ph;
}

// ---------- pure NT GEMM single bf16, fp32 output: C = A @ B^T ----------
__global__ __launch_bounds__(256) void gemm_nt_f32_kernel(
    const u16* __restrict__ A, long sAb, int lda,
    const u16* __restrict__ B, long sBb, int ldb,
    float* __restrict__ Cout, long sCb, int ldc, int ntj, int K) {
  int b = blockIdx.y;
  int ti = blockIdx.x / ntj, tj = blockIdx.x % ntj;
  int i0 = ti * 128, j0 = tj * 128;
  const u16* Ab = A + (size_t)b * sAb;
  const u16* Bb = B + (size_t)b * sBb;
  __shared__ __align__(16) u16 As[4096], Bs[4096];
  int t = threadIdx.x, l = t & 63, w = t >> 6;
  int wr = w >> 1, wc = w & 1;
  int r0 = t >> 2, ce = (t & 3) * 8;
  f32x4 acc[4][4] = {};
  for (int kt = 0; kt < K; kt += 32) {
    __syncthreads();
    gl16(Ab + (size_t)(i0 + r0) * lda + kt + ce, (char*)As + t * 16);
    gl16(Ab + (size_t)(i0 + 64 + r0) * lda + kt + ce, (char*)As + 4096 + t * 16);
    gl16(Bb + (size_t)(j0 + r0) * ldb + kt + ce, (char*)Bs + t * 16);
    gl16(Bb + (size_t)(j0 + 64 + r0) * ldb + kt + ce, (char*)Bs + 4096 + t * 16);
    __syncthreads();
    bf16x8 ah[4], bh[4];
#pragma unroll
    for (int m = 0; m < 4; ++m) {
      int row = wr * 64 + m * 16 + (l & 15);
      ah[m] = *(const bf16x8*)((const char*)As + row * 64 + (l >> 4) * 16);
    }
#pragma unroll
    for (int n = 0; n < 4; ++n) {
      int row = wc * 64 + n * 16 + (l & 15);
      bh[n] = *(const bf16x8*)((const char*)Bs + row * 64 + (l >> 4) * 16);
    }
#pragma unroll
    for (int m = 0; m < 4; ++m)
#pragma unroll
      for (int n = 0; n < 4; ++n)
        acc[m][n] = MFMA16(ah[m], bh[n], acc[m][n]);
  }
#pragma unroll
  for (int m = 0; m < 4; ++m) {
    int rb = i0 + wr * 64 + m * 16 + (l >> 4) * 4;
#pragma unroll
    for (int n = 0; n < 4; ++n) {
      int col = j0 + wc * 64 + n * 16 + (l & 15);
#pragma unroll
      for (int j = 0; j < 4; ++j)
        Cout[(size_t)b * sCb + (size_t)(rb + j) * ldc + col] = acc[m][n][j];
    }
  }
}

// ---------- pure NT GEMM single bf16, bf16 output: C = A @ B^T ----------
__global__ __launch_bounds__(256) void gemm_nt_bf16_kernel(
    const u16* __restrict__ A, long sAb, int lda,
    const u16* __restrict__ B, long sBb, int ldb,
    u16* __restrict__ outB, long sCb, int ldc, int ntj, int K) {
  int b = blockIdx.y;
  int ti = blockIdx.x / ntj, tj = blockIdx.x % ntj;
  int i0 = ti * 128, j0 = tj * 128;
  const u16* Ab = A + (size_t)b * sAb;
  const u16* Bb = B + (size_t)b * sBb;
  __shared__ __align__(16) u16 As[4096], Bs[4096];
  int t = threadIdx.x, l = t & 63, w = t >> 6;
  int wr = w >> 1, wc = w & 1;
  int r0 = t >> 2, ce = (t & 3) * 8;
  f32x4 acc[4][4] = {};
  for (int kt = 0; kt < K; kt += 32) {
    __syncthreads();
    gl16(Ab + (size_t)(i0 + r0) * lda + kt + ce, (char*)As + t * 16);
    gl16(Ab + (size_t)(i0 + 64 + r0) * lda + kt + ce, (char*)As + 4096 + t * 16);
    gl16(Bb + (size_t)(j0 + r0) * ldb + kt + ce, (char*)Bs + t * 16);
    gl16(Bb + (size_t)(j0 + 64 + r0) * ldb + kt + ce, (char*)Bs + 4096 + t * 16);
    __syncthreads();
    bf16x8 ah[4], bh[4];
#pragma unroll
    for (int m = 0; m < 4; ++m) {
      int row = wr * 64 + m * 16 + (l & 15);
      ah[m] = *(const bf16x8*)((const char*)As + row * 64 + (l >> 4) * 16);
    }
#pragma unroll
    for (int n = 0; n < 4; ++n) {
      int row = wc * 64 + n * 16 + (l & 15);
      bh[n] = *(const bf16x8*)((const char*)Bs + row * 64 + (l >> 4) * 16);
    }
#pragma unroll
    for (int m = 0; m < 4; ++m)
#pragma unroll
      for (int n = 0; n < 4; ++n)
        acc[m][n] = MFMA16(ah[m], bh[n], acc[m][n]);
  }
  u16* Ob = outB + (size_t)b * sCb;
#pragma unroll
  for (int m = 0; m < 4; ++m) {
    int rb = i0 + wr * 64 + m * 16 + (l >> 4) * 4;
#pragma unroll
    for (int n = 0; n < 4; ++n) {
      int col = j0 + wc * 64 + n * 16 + (l & 15);
#pragma unroll
      for (int j = 0; j < 4; ++j)
        Ob[(size_t)(rb + j) * ldc + col] = (u16)f2bf_u(acc[m][n][j]);
    }
  }
}

// ---------- attention per (b,h): S = QG.Wk^T + bias; softmax; Pt = (att @ Wv)^T ----------
__global__ __launch_bounds__(256) void attn_kernel(
    const float* __restrict__ QG, const float* __restrict__ w_qkv,
    const float* __restrict__ b_qkv, const float* __restrict__ svec,
    u16* __restrict__ Pt, float* __restrict__ u) {
  int h = blockIdx.x, b = blockIdx.y;
  __shared__ float s_sh[512];
  __shared__ float qs[64], ks[64], bqv[64], bkv[64], bvv[64];
  __shared__ float pool[4096];
  __shared__ float att[64][66];
  int t = threadIdx.x, tx = t & 15, ty = t >> 4;
  for (int i = t; i < 512; i += 256) s_sh[i] = svec[b * C_DIM + i];
  if (t < 64) {
    bqv[t] = b_qkv[h * 64 + t];
    bkv[t] = b_qkv[512 + h * 64 + t];
    bvv[t] = b_qkv[1024 + h * 64 + t];
  }
  __syncthreads();
  if (t < 64) {
    const float* wr = w_qkv + (size_t)(h * 64 + t) * C_DIM;
    float a = 0.f;
    for (int c = 0; c < 512; ++c) a += wr[c] * s_sh[c];
    qs[t] = a;
  } else if (t < 128) {
    int e = t - 64;
    const float* wr = w_qkv + (size_t)(512 + h * 64 + e) * C_DIM;
    float a = 0.f;
    for (int c = 0; c < 512; ++c) a += wr[c] * s_sh[c];
    ks[e] = a;
  }
  __syncthreads();
  float acc[4][4] = {};
  float* As = pool;
  float* Bs = pool + 2048;
  for (int kt = 0; kt < 512; kt += 32) {
#pragma unroll
    for (int r = 0; r < 2; ++r) {
      int idx = t + r * 256;
      int row = idx >> 3, c4 = (idx & 7) * 4;
      float4 va = *(const float4*)(QG + ((size_t)b * 512 + h * 64 + row) * 512 + kt + c4);
      As[(c4 + 0) * 64 + row] = va.x; As[(c4 + 1) * 64 + row] = va.y;
      As[(c4 + 2) * 64 + row] = va.z; As[(c4 + 3) * 64 + row] = va.w;
      float4 vb = *(const float4*)(w_qkv + (size_t)(512 + h * 64 + row) * 512 + kt + c4);
      Bs[(c4 + 0) * 64 + row] = vb.x; Bs[(c4 + 1) * 64 + row] = vb.y;
      Bs[(c4 + 2) * 64 + row] = vb.z; Bs[(c4 + 3) * 64 + row] = vb.w;
    }
    __syncthreads();
#pragma unroll 4
    for (int k = 0; k < 32; ++k) {
      float4 a4 = *(const float4*)&As[k * 64 + ty * 4];
      float4 b4 = *(const float4*)&Bs[k * 64 + tx * 4];
      float ar[4] = {a4.x, a4.y, a4.z, a4.w};
      float br[4] = {b4.x, b4.y, b4.z, b4.w};
#pragma unroll
      for (int i = 0; i < 4; ++i)
#pragma unroll
        for (int j = 0; j < 4; ++j) acc[i][j] += ar[i] * br[j];
    }
    __syncthreads();
  }
#pragma unroll
  for (int i = 0; i < 4; ++i) {
    int d = ty * 4 + i;
#pragma unroll
    for (int j = 0; j < 4; ++j) {
      int e = tx * 4 + j;
      float raw = acc[i][j] + bqv[d] * ks[e] + bkv[e] * qs[d] + 4096.0f * bqv[d] * bkv[e];
      att[d][e] = raw * 0.125f;
    }
  }
  __syncthreads();
  if (t < 64) {
    float m = -1e30f;
    for (int e = 0; e < 64; ++e) m = fmaxf(m, att[t][e]);
    float ssum = 0.f;
    for (int e = 0; e < 64; ++e) { float p = expf(att[t][e] - m); att[t][e] = p; ssum += p; }
    float inv = 1.0f / ssum;
    for (int e = 0; e < 64; ++e) att[t][e] *= inv;
  }
  __syncthreads();
  float* Ws = pool;
  for (int cc = 0; cc < 512; cc += 64) {
#pragma unroll
    for (int r = 0; r < 4; ++r) {
      int idx = t + r * 256;
      int row = idx >> 4, c4 = (idx & 15) * 4;
      *(float4*)&Ws[row * 64 + c4] =
          *(const float4*)(w_qkv + (size_t)(1024 + h * 64 + row) * 512 + cc + c4);
    }
    __syncthreads();
    float pacc[4][4] = {};
#pragma unroll 4
    for (int e = 0; e < 64; ++e) {
      float a0 = att[ty * 4 + 0][e], a1 = att[ty * 4 + 1][e];
      float a2 = att[ty * 4 + 2][e], a3 = att[ty * 4 + 3][e];
      float4 b4 = *(const float4*)&Ws[e * 64 + tx * 4];
      float br[4] = {b4.x, b4.y, b4.z, b4.w};
#pragma unroll
      for (int j = 0; j < 4; ++j) {
        pacc[0][j] += a0 * br[j]; pacc[1][j] += a1 * br[j];
        pacc[2][j] += a2 * br[j]; pacc[3][j] += a3 * br[j];
      }
    }
    // Pt[b][c][r] = P[r][c]  (bf16)
#pragma unroll
    for (int j = 0; j < 4; ++j) {
      uint2 pk;
      pk.x = f2bf_u(pacc[0][j]) | (f2bf_u(pacc[1][j]) << 16);
      pk.y = f2bf_u(pacc[2][j]) | (f2bf_u(pacc[3][j]) << 16);
      *(uint2*)&Pt[((size_t)b * 512 + cc + tx * 4 + j) * 512 + h * 64 + ty * 4] = pk;
    }
    __syncthreads();
  }
  if (t < 64) {
    float a = 0.f;
    for (int e = 0; e < 64; ++e) a += att[t][e] * bvv[e];
    u[b * C_DIM + h * 64 + t] = a;
  }
}

// ---------- cvec_b = w_out @ u_b + b_out ----------
__global__ __launch_bounds__(256) void cvec_kernel(
    const float* __restrict__ w_out, const float* __restrict__ b_out,
    const float* __restrict__ u, float* __restrict__ cvec) {
  int b = blockIdx.x;
  __shared__ float us[512];
  int t = threadIdx.x;
  for (int i = t; i < 512; i += 256) us[i] = u[b * C_DIM + i];
  __syncthreads();
  for (int o = t; o < 512; o += 256) {
    const float* wr = w_out + (size_t)o * C_DIM;
    float a = 0.f;
    for (int r = 0; r < 512; ++r) a += wr[r] * us[r];
    cvec[b * C_DIM + o] = a + b_out[o];
  }
}

// ---------- final fused: out = x + M @ h + cvec   (A=Mbf gl16; B from x, transposed) ----------
// grid (4*32 tiles, 16 batch)
__global__ __launch_bounds__(256) void final_fused_kernel(
    const u16* __restrict__ Mbf, const float* __restrict__ x,
    const float* __restrict__ na, const float* __restrict__ nd,
    const float* __restrict__ cvec, float* __restrict__ out) {
  int b = blockIdx.y;
  int ti = blockIdx.x >> 5, tj = blockIdx.x & 31;
  int i0 = ti * 128, n0 = tj * 128;
  const u16* Mb = Mbf + (size_t)b * 512 * 512;
  const float* xb = x + (size_t)b * C_DIM * N_DIM;
  float* ob = out + (size_t)b * C_DIM * N_DIM;
  __shared__ __align__(16) u16 As[4096], Bs[4096];
  int t = threadIdx.x, l = t & 63, w = t >> 6;
  int wr = w >> 1, wc = w & 1;
  int r0 = t >> 2, ce = (t & 3) * 8;
  int c0 = (t >> 5) * 4, n4 = (t & 31) * 4;
  f32x4 acc[4][4] = {};
  float4 q0, q1, q2, q3;
  q0 = *(const float4*)(xb + (size_t)(c0 + 0) * N_DIM + n0 + n4);
  q1 = *(const float4*)(xb + (size_t)(c0 + 1) * N_DIM + n0 + n4);
  q2 = *(const float4*)(xb + (size_t)(c0 + 2) * N_DIM + n0 + n4);
  q3 = *(const float4*)(xb + (size_t)(c0 + 3) * N_DIM + n0 + n4);
  for (int kt = 0; kt < 512; kt += 32) {
    __syncthreads();
    gl16(Mb + (size_t)(i0 + r0) * 512 + kt + ce, (char*)As + t * 16);
    gl16(Mb + (size_t)(i0 + 64 + r0) * 512 + kt + ce, (char*)As + 4096 + t * 16);
    {
      float ac[4], dc[4];
#pragma unroll
      for (int cc = 0; cc < 4; ++cc) {
        ac[cc] = na[b * C_DIM + kt + c0 + cc];
        dc[cc] = nd[b * C_DIM + kt + c0 + cc];
      }
      const float* f0 = (const float*)&q0;
      const float* f1 = (const float*)&q1;
      const float* f2 = (const float*)&q2;
      const float* f3 = (const float*)&q3;
#pragma unroll
      for (int e = 0; e < 4; ++e) {
        int n = n4 + e;
        unsigned b0 = f2bf_u(ac[0] * f0[e] + dc[0]);
        unsigned b1 = f2bf_u(ac[1] * f1[e] + dc[1]);
        unsigned b2 = f2bf_u(ac[2] * f2[e] + dc[2]);
        unsigned b3 = f2bf_u(ac[3] * f3[e] + dc[3]);
        uint2 pk; pk.x = b0 | (b1 << 16); pk.y = b2 | (b3 << 16);
        int off = (n * 64 + c0 * 2) ^ ((n & 7) << 4);
        *(uint2*)((char*)Bs + off) = pk;
      }
    }
    if (kt + 32 < 512) {
      q0 = *(const float4*)(xb + (size_t)(kt + 32 + c0 + 0) * N_DIM + n0 + n4);
      q1 = *(const float4*)(xb + (size_t)(kt + 32 + c0 + 1) * N_DIM + n0 + n4);
      q2 = *(const float4*)(xb + (size_t)(kt + 32 + c0 + 2) * N_DIM + n0 + n4);
      q3 = *(const float4*)(xb + (size_t)(kt + 32 + c0 + 3) * N_DIM + n0 + n4);
    }
    __syncthreads();
    bf16x8 ah[4], bh[4];
#pragma unroll
    for (int m = 0; m < 4; ++m) {
      int row = wr * 64 + m * 16 + (l & 15);
      ah[m] = *(const bf16x8*)((const char*)As + row * 64 + (l >> 4) * 16);
    }
#pragma unroll
    for (int n = 0; n < 4; ++n) {
      int row = wc * 64 + n * 16 + (l & 15);
      int off = (row * 64 + (l >> 4) * 16) ^ ((row & 7) << 4);
      bh[n] = *(const bf16x8*)((const char*)Bs + off);
    }
#pragma unroll
    for (int m = 0; m < 4; ++m)
#pragma unroll
      for (int n = 0; n < 4; ++n)
        acc[m][n] = MFMA16(ah[m], bh[n], acc[m][n]);
  }
#pragma unroll
  for (int m = 0; m < 4; ++m) {
    int rb = i0 + wr * 64 + m * 16 + (l >> 4) * 4;
#pragma unroll
    for (int n = 0; n < 4; ++n) {
      int col = n0 + wc * 64 + n * 16 + (l & 15);
#pragma unroll
      for (int j = 0; j < 4; ++j) {
        size_t off = (size_t)(rb + j) * N_DIM + col;
        ob[off] = acc[m][n][j] + xb[off] + cvec[b * C_DIM + rb + j];
      }
    }
  }
}

extern "C" void kernel_launch(void* const* d_in, const int* in_sizes, int n_in,
                              void* d_out, int out_size, void* d_ws, size_t ws_size,
                              hipStream_t stream) {
  const float* x     = (const float*)d_in[0];
  const float* gamma = (const float*)d_in[1];
  const float* beta  = (const float*)d_in[2];
  const float* w_qkv = (const float*)d_in[3];
  const float* b_qkv = (const float*)d_in[4];
  const float* w_out = (const float*)d_in[5];
  const float* b_out = (const float*)d_in[6];
  float* out = (float*)d_out;

  char* wp = (char*)d_ws;
  double* chsum = (double*)wp; wp += 8192 * 8;
  double* chsq  = (double*)wp; wp += 8192 * 8;
  float* a_coef = (float*)wp; wp += 8192 * 4;
  float* d_coef = (float*)wp; wp += 8192 * 4;
  float* svec   = (float*)wp; wp += 8192 * 4;
  float* uvec   = (float*)wp; wp += 8192 * 4;
  float* cvec   = (float*)wp; wp += 8192 * 4;
  u16* wqb   = (u16*)wp; wp += 262144 * 2;
  u16* woutb = (u16*)wp; wp += 262144 * 2;
  float* Gp = (float*)wp; wp += (size_t)2 * 16 * 512 * 512 * 4;   // 33.55 MB
  u16* Ghi = (u16*)wp; wp += (size_t)16 * 512 * 512 * 2;          // 8.39 MB
  // aliases (liveness-disjoint)
  float* QG = Gp;                                                  // after gsum
  u16* Pt = (u16*)(Gp + (size_t)16 * 512 * 512);                   // 2nd half of Gp
  u16* Mbf = Ghi;                                                  // after QG-GEMM

  channel_stats_kernel<<<BATCH * C_DIM, 256, 0, stream>>>(x, chsum, chsq);
  group_stats_kernel<<<BATCH * NGROUPS, 64, 0, stream>>>(chsum, chsq, gamma, beta,
                                                         a_coef, d_coef, svec);
  wprep_kernel<<<256, 256, 0, stream>>>(w_qkv, w_out, wqb, woutb);
  // G partials (ksplit=2), single-pass bf16
  gram_fused_kernel<<<dim3(16, BATCH, 2), 256, 0, stream>>>(x, a_coef, d_coef, Gp);
  gsum_kernel<<<4096, 256, 0, stream>>>(Gp, Gp + (size_t)16 * 512 * 512, Ghi);
  // QG = Wq @ G  (G symmetric -> NT with B rows = G rows), single-pass bf16
  gemm_nt_f32_kernel<<<dim3(16, BATCH), 256, 0, stream>>>(
      wqb, 0, 512, Ghi, 512 * 512, 512, QG, 512 * 512, 512, 4, 512);
  attn_kernel<<<dim3(NHEADS, BATCH), 256, 0, stream>>>(QG, w_qkv, b_qkv, svec, Pt, uvec);
  cvec_kernel<<<BATCH, 256, 0, stream>>>(w_out, b_out, uvec, cvec);
  // M = Wout @ P  == NT(A=Wout[o][r], B=Pt[c][r]); bf16 out
  gemm_nt_bf16_kernel<<<dim3(16, BATCH), 256, 0, stream>>>(
      woutb, 0, 512, Pt, 512 * 512, 512, Mbf, 512 * 512, 512, 4, 512);
  // out = x + M @ h + cvec
  final_fused_kernel<<<dim3(128, BATCH), 256, 0, stream>>>(Mbf, x, a_coef, d_coef, cvec, out);
}